// Round 4
// baseline (1195.936 us; speedup 1.0000x reference)
//
#include <hip/hip_runtime.h>
#include <stdint.h>

typedef __attribute__((ext_vector_type(8))) short short8;
typedef __attribute__((ext_vector_type(4))) float f32x4;

__device__ __forceinline__ unsigned short f2bf(float f) {
  union { float f; uint32_t u; } v; v.f = f;
  uint32_t u = v.u;
  u += 0x7FFF + ((u >> 16) & 1);   // round-to-nearest-even
  return (unsigned short)(u >> 16);
}
__device__ __forceinline__ float bf2f(unsigned short h) {
  union { uint32_t u; float f; } v; v.u = ((uint32_t)h) << 16;
  return v.f;
}

// ---------------- convert fp32 -> bf16 (8 elems/thread) -------------------
__global__ void conv_kernel(const float* __restrict__ in,
                            unsigned short* __restrict__ out, int n) {
  long i = ((long)blockIdx.x * blockDim.x + threadIdx.x) * 8;
  if (i >= n) return;
  float4 a = *(const float4*)(in + i);
  float4 b = *(const float4*)(in + i + 4);
  short8 s;
  s[0] = (short)f2bf(a.x); s[1] = (short)f2bf(a.y);
  s[2] = (short)f2bf(a.z); s[3] = (short)f2bf(a.w);
  s[4] = (short)f2bf(b.x); s[5] = (short)f2bf(b.y);
  s[6] = (short)f2bf(b.z); s[7] = (short)f2bf(b.w);
  *(short8*)(out + i) = s;
}

// convert with per-column scale fold: out[i] = bf16(in[i] * scale[i & 2047])
__global__ void convs_kernel(const float* __restrict__ in,
                             const float* __restrict__ scale,
                             unsigned short* __restrict__ out, int n) {
  long i = ((long)blockIdx.x * blockDim.x + threadIdx.x) * 8;
  if (i >= n) return;
  short8 s;
#pragma unroll
  for (int j = 0; j < 8; ++j)
    s[j] = (short)f2bf(in[i + j] * scale[(i + j) & 2047]);
  *(short8*)(out + i) = s;
}

// transpose-convert: out[C][R] = bf16(in[R][C]^T).  block (32,8), grid (C/32, R/32)
__global__ void tconv_kernel(const float* __restrict__ in, int R, int C,
                             unsigned short* __restrict__ out) {
  __shared__ float tile[32][33];
  int c0 = blockIdx.x * 32, r0 = blockIdx.y * 32;
  int tx = threadIdx.x, ty = threadIdx.y;
#pragma unroll
  for (int i = 0; i < 32; i += 8)
    tile[ty + i][tx] = in[(long)(r0 + ty + i) * C + c0 + tx];
  __syncthreads();
#pragma unroll
  for (int i = 0; i < 32; i += 8)
    out[(long)(c0 + ty + i) * R + r0 + tx] = f2bf(tile[tx][ty + i]);
}

// ---------------- 256x256 bf16 GEMM, 8-phase schedule ---------------------
// C = A @ W^T (+ epilogue). BK=64, 8 waves (2M x 4N), interleaved frag map
// (A frag m -> row (m>>2)*128+(m&3)*32+wm*16; B frag n -> col
// (n>>1)*128+(n&1)*64+wn*16) so each LDS half is consumed by known phases.
// LDS: 2 bufs x (A:2 + B:2 halves) x 16KB = 128KB, chunk-XOR swizzled.
// Counted vmcnt, never 0 mid-loop. KSPLIT: k>=KSPLIT reads A2/W2.
// PAIR: blocks >= pairBase shift A/W/C by aoff/woff/coff (ushort elements).
enum { EPI_BIAS = 0, EPI_GATE = 2, EPI_LNF32 = 4 };

#define VMW(N) asm volatile("s_waitcnt vmcnt(" #N ")" ::: "memory")
#define SBAR() __builtin_amdgcn_s_barrier()

template <int EPI, int SWZ>
__global__ __launch_bounds__(512, 2)
void gemm8p_kernel(const unsigned short* __restrict__ A1,
                   const unsigned short* __restrict__ A2, int lda,
                   const unsigned short* __restrict__ W1,
                   const unsigned short* __restrict__ W2, int ldw,
                   int K, int KSPLIT, int ldc, int nmt,
                   int pairBase, long aoff, long woff, long coff,
                   const float* __restrict__ bias,
                   const float* __restrict__ bias2,
                   const unsigned short* __restrict__ Xg,
                   const unsigned short* __restrict__ Xc,
                   const float2* __restrict__ stats,
                   void* __restrict__ Cv) {
  __shared__ unsigned short smem[65536];  // 128 KB

  const int tid = threadIdx.x, lane = tid & 63, w = tid >> 6;
  const int wm = w >> 2, wn = w & 3;

  int bid = blockIdx.x;
  if (bid >= pairBase) {
    bid -= pairBase;
    A1 += aoff; A2 += aoff; W1 += woff; W2 += woff;
    Cv = (void*)((unsigned short*)Cv + coff);
  }
  int mt, nt;
  if (SWZ) {  // 512 blocks: XCD x owns mt [x*8, x*8+8), sweeps 8 nt
    const int xcd = bid & 7, seq = bid >> 3;
    nt = seq >> 3;
    mt = xcd * 8 + (seq & 7);
  } else {
    mt = bid % nmt;
    nt = bid / nmt;
  }
  const long tileM = (long)mt * 256, tileN = (long)nt * 256;

  // staging source (per lane): region w*2+j covers rows w*16+j*8..+7 of a
  // [128][64] half; lane -> row +(l>>3), chunk (l&7)^((l>>3)&7) (inv swizzle)
  const int sRow = w * 16 + (lane >> 3);
  const int sCol = (((lane & 7) ^ ((lane >> 3) & 7)) * 8);
  const unsigned short* aS1 = A1 + (tileM + sRow) * (long)lda + sCol;
  const unsigned short* aS2 = A2 + (tileM + sRow) * (long)lda + sCol;
  const unsigned short* bS1 = W1 + (tileN + sRow) * (long)ldw + sCol;
  const unsigned short* bS2 = W2 + (tileN + sRow) * (long)ldw + sCol;

  auto stage = [&](int op, int half, int d, int kt) {
    long k = (long)kt * 64;
    long ld = op ? (long)ldw : (long)lda;
    const unsigned short* p;
    if (op == 0) p = (k < KSPLIT) ? (aS1 + k) : (aS2 + (k - KSPLIT));
    else         p = (k < KSPLIT) ? (bS1 + k) : (bS2 + (k - KSPLIT));
    p += (long)half * 128 * ld;
    char* lp = (char*)smem + (d * 65536 + op * 32768 + half * 16384 + w * 2048);
    __builtin_amdgcn_global_load_lds(
        (const __attribute__((address_space(1))) void*)p,
        (__attribute__((address_space(3))) void*)lp, 16, 0, 0);
    __builtin_amdgcn_global_load_lds(
        (const __attribute__((address_space(1))) void*)(p + 8 * ld),
        (__attribute__((address_space(3))) void*)(lp + 1024), 16, 0, 0);
  };

  const int fr = lane & 15, kc = lane >> 4, l7 = lane & 7;
  auto rdA = [&](int d, int m, int kk) -> short8 {
    unsigned off = d * 65536 + (m >> 2) * 16384
                 + (((m & 3) * 32 + wm * 16 + fr) * 128)
                 + ((((kk * 4 + kc) ^ l7)) * 16);
    return *(const short8*)((const char*)smem + off);
  };
  auto rdB = [&](int d, int n, int kk) -> short8 {
    unsigned off = d * 65536 + 32768 + (n >> 1) * 16384
                 + (((n & 1) * 64 + wn * 16 + fr) * 128)
                 + ((((kk * 4 + kc) ^ l7)) * 16);
    return *(const short8*)((const char*)smem + off);
  };

  f32x4 acc[8][4] = {};
  short8 aH[4][2];

#define PHASE(D, MQ, NQ, LOADA, DOSTAGE, SOP, SHALF, SD, SKT)                 \
  {                                                                           \
    if (LOADA) {                                                              \
      _Pragma("unroll") for (int mi = 0; mi < 4; ++mi)                        \
      _Pragma("unroll") for (int kk = 0; kk < 2; ++kk)                        \
          aH[mi][kk] = rdA(D, (MQ)*4 + mi, kk);                               \
    }                                                                         \
    short8 bq[2][2];                                                          \
    _Pragma("unroll") for (int ni = 0; ni < 2; ++ni)                          \
    _Pragma("unroll") for (int kk = 0; kk < 2; ++kk)                          \
        bq[ni][kk] = rdB(D, (NQ)*2 + ni, kk);                                 \
    if (DOSTAGE) stage(SOP, SHALF, SD, SKT);                                  \
    SBAR();                                                                   \
    __builtin_amdgcn_s_setprio(1);                                            \
    _Pragma("unroll") for (int mi = 0; mi < 4; ++mi)                          \
    _Pragma("unroll") for (int ni = 0; ni < 2; ++ni) {                        \
      acc[(MQ)*4+mi][(NQ)*2+ni] = __builtin_amdgcn_mfma_f32_16x16x32_bf16(    \
          aH[mi][0], bq[ni][0], acc[(MQ)*4+mi][(NQ)*2+ni], 0, 0, 0);          \
      acc[(MQ)*4+mi][(NQ)*2+ni] = __builtin_amdgcn_mfma_f32_16x16x32_bf16(    \
          aH[mi][1], bq[ni][1], acc[(MQ)*4+mi][(NQ)*2+ni], 0, 0, 0);          \
    }                                                                         \
    __builtin_amdgcn_s_setprio(0);                                            \
  }

  // ---- prologue (steady-state aging order) --------------------------------
  stage(0, 0, 0, 0);  // b0.A0 t0
  stage(1, 0, 0, 0);  // b0.B0 t0
  stage(1, 1, 0, 0);  // b0.B1 t0
  stage(0, 1, 0, 0);  // b0.A1 t0
  stage(0, 0, 1, 1);  // b1.A0 t1
  stage(1, 0, 1, 1);  // b1.B0 t1
  VMW(8);
  SBAR();

  const int NIT = K / 128;  // 2 K-tiles (BK=64) per iteration
  for (int it = 0; it < NIT - 1; ++it) {
    PHASE(0, 0, 0, 1, true, 1, 1, 1, 2 * it + 1); VMW(8); SBAR();
    PHASE(0, 0, 1, 0, true, 0, 0, 0, 2 * it + 2); VMW(8); SBAR();
    PHASE(0, 1, 0, 1, true, 0, 1, 1, 2 * it + 1);         SBAR();
    PHASE(0, 1, 1, 0, true, 1, 0, 0, 2 * it + 2); VMW(8); SBAR();
    PHASE(1, 0, 0, 1, true, 1, 1, 0, 2 * it + 2); VMW(8); SBAR();
    PHASE(1, 0, 1, 0, true, 0, 1, 0, 2 * it + 2); VMW(6); SBAR();
    PHASE(1, 1, 0, 1, true, 0, 0, 1, 2 * it + 3);         SBAR();
    PHASE(1, 1, 1, 0, true, 1, 0, 1, 2 * it + 3); VMW(8); SBAR();
  }
  {  // peeled drain iteration
    const int itL = NIT - 1;
    PHASE(0, 0, 0, 1, true,  1, 1, 1, 2 * itL + 1); VMW(8); SBAR();
    PHASE(0, 0, 1, 0, false, 0, 0, 0, 0);           VMW(6); SBAR();
    PHASE(0, 1, 0, 1, true,  0, 1, 1, 2 * itL + 1);         SBAR();
    PHASE(0, 1, 1, 0, false, 0, 0, 0, 0);           VMW(4); SBAR();
    PHASE(1, 0, 0, 1, false, 0, 0, 0, 0);           VMW(2); SBAR();
    PHASE(1, 0, 1, 0, false, 0, 0, 0, 0);           VMW(0); SBAR();
    PHASE(1, 1, 0, 1, false, 0, 0, 0, 0);                   SBAR();
    PHASE(1, 1, 1, 0, false, 0, 0, 0, 0);
  }
#undef PHASE

  // ---- epilogue: C/D layout col = lane&15, row = (lane>>4)*4 + reg --------
  const int cr = (lane >> 4) * 4;
  const int cc = lane & 15;
#pragma unroll
  for (int m = 0; m < 8; ++m) {
    long rr = tileM + (m >> 2) * 128 + (m & 3) * 32 + wm * 16 + cr;
#pragma unroll
    for (int n = 0; n < 4; ++n) {
      long c = tileN + (n >> 1) * 128 + (n & 1) * 64 + wn * 16 + cc;
      float b1 = bias ? bias[c] : 0.0f;
      float b2 = bias2 ? bias2[c] : 0.0f;
#pragma unroll
      for (int r = 0; r < 4; ++r) {
        long row = rr + r;
        long idx = row * (long)ldc + c;
        float v = acc[m][n][r];
        if constexpr (EPI == EPI_BIAS) {
          ((unsigned short*)Cv)[idx] = f2bf(v + b1 + b2);
        }
        if constexpr (EPI == EPI_GATE) {
          float gt = 1.0f / (1.0f + expf(-(v + b1)));
          float gv = bf2f(Xg[idx]);   // g
          float cvv = bf2f(Xc[idx]);  // cross
          ((unsigned short*)Cv)[idx] = f2bf(gt * gv + (1.0f - gt) * cvv + gv);
        }
        if constexpr (EPI == EPI_LNF32) {
          float2 st = stats[row];  // (mu, rstd)
          ((float*)Cv)[idx] = v * st.y - st.y * st.x * b1 + b2;
        }
      }
    }
  }
}

// ---------------- per-row LN stats over 2048 cols -------------------------
__global__ __launch_bounds__(256) void lnstats_kernel(
    const unsigned short* __restrict__ in, float2* __restrict__ stats) {
  const int row = blockIdx.x;
  const int t = threadIdx.x, lane = t & 63, wave = t >> 6;
  short8 v8 = *(const short8*)&in[(long)row * 2048 + t * 8];
  float s = 0.f, s2 = 0.f;
#pragma unroll
  for (int j = 0; j < 8; ++j) {
    float x = bf2f((unsigned short)v8[j]);
    s += x; s2 += x * x;
  }
#pragma unroll
  for (int off = 1; off < 64; off <<= 1) {
    s  += __shfl_xor(s, off);
    s2 += __shfl_xor(s2, off);
  }
  __shared__ float red[8];
  if (lane == 0) { red[wave] = s; red[4 + wave] = s2; }
  __syncthreads();
  if (t == 0) {
    float ts  = red[0] + red[1] + red[2] + red[3];
    float ts2 = red[4] + red[5] + red[6] + red[7];
    float mean = ts * (1.0f / 2048.0f);
    float var  = ts2 * (1.0f / 2048.0f) - mean * mean;
    stats[row] = make_float2(mean, rsqrtf(var + 1e-5f));
  }
}

// bcV[c] = (wO1@bv1 + wO2@bv2 + Wc1@tp_b + Wc2@gp_b)[c] + out1_b[c] + out2_b[c]
__global__ void biascomp_kernel(const unsigned short* __restrict__ wO1b,
                                const unsigned short* __restrict__ wO2b,
                                const unsigned short* __restrict__ Wc1,
                                const unsigned short* __restrict__ Wc2,
                                const float* __restrict__ bv1,
                                const float* __restrict__ bv2,
                                const float* __restrict__ tpb,
                                const float* __restrict__ gpb,
                                const float* __restrict__ o1b,
                                const float* __restrict__ o2b,
                                float* __restrict__ bcV) {
  int c = blockIdx.x * 256 + threadIdx.x;
  float s = o1b[c] + o2b[c];
  const unsigned short* r1 = wO1b + (long)c * 2048;
  const unsigned short* r2 = wO2b + (long)c * 2048;
  const unsigned short* r3 = Wc1 + (long)c * 2048;
  const unsigned short* r4 = Wc2 + (long)c * 2048;
  for (int k = 0; k < 2048; ++k)
    s += bf2f(r1[k]) * bv1[k] + bf2f(r2[k]) * bv2[k]
       + bf2f(r3[k]) * tpb[k] + bf2f(r4[k]) * gpb[k];
  bcV[c] = s;
}

// u[n] = rowsum(W'γ-folded);  v[n] = dot(ln_beta, lin_w[n,:]) + lin_b[n]
__global__ void uv_kernel(const unsigned short* __restrict__ wlinp,
                          const float* __restrict__ lin_w,
                          const float* __restrict__ ln_beta,
                          const float* __restrict__ lin_b,
                          float* __restrict__ uV, float* __restrict__ vV) {
  int n = blockIdx.x * 256 + threadIdx.x;
  float u = 0.f, v = 0.f;
  const unsigned short* r1 = wlinp + (long)n * 2048;
  const float* r2 = lin_w + (long)n * 2048;
  for (int k = 0; k < 2048; ++k) {
    u += bf2f(r1[k]);
    v += ln_beta[k] * r2[k];
  }
  uV[n] = u;
  vV[n] = v + lin_b[n];
}

// --------------------------------------------------------------------------
extern "C" void kernel_launch(void* const* d_in, const int* in_sizes, int n_in,
                              void* d_out, int out_size, void* d_ws, size_t ws_size,
                              hipStream_t stream) {
  const float* graph    = (const float*)d_in[0];
  const float* temporal = (const float*)d_in[1];
  const float* gp_w  = (const float*)d_in[2];
  const float* gp_b  = (const float*)d_in[3];
  const float* tp_w  = (const float*)d_in[4];
  const float* tp_b  = (const float*)d_in[5];
  const float* in1_w = (const float*)d_in[6];
  const float* in1_b = (const float*)d_in[7];
  const float* out1_w = (const float*)d_in[8];
  const float* out1_b = (const float*)d_in[9];
  const float* in2_w = (const float*)d_in[10];
  const float* in2_b = (const float*)d_in[11];
  const float* out2_w = (const float*)d_in[12];
  const float* out2_b = (const float*)d_in[13];
  const float* gate_w = (const float*)d_in[14];
  const float* gate_b = (const float*)d_in[15];
  const float* ln_g  = (const float*)d_in[16];
  const float* ln_b  = (const float*)d_in[17];
  const float* lin_w = (const float*)d_in[18];
  const float* lin_b = (const float*)d_in[19];

  const int Bm = 16384, F = 2048, GD = 1024;
  const long BF = (long)Bm * F, FF = (long)F * F, FG = (long)F * GD;

  // ---- ws layout (~248 MB) ----
  unsigned short* S0  = (unsigned short*)d_ws;   // g
  unsigned short* S1  = S0 + BF;                 // cross
  unsigned short* inG = S1 + BF;                 // graph bf16; later preLN base
  unsigned short* inT = inG + (long)Bm * GD;     // temporal bf16
  unsigned short* PL  = inG;                     // preLN reuses inG+inT (BF elems)
  unsigned short* wGP   = inT + (long)Bm * GD;
  unsigned short* wO1b  = wGP + FG;
  unsigned short* wO2b  = wO1b + FF;
  unsigned short* wGATE = wO2b + FF;
  unsigned short* wLIN  = wGATE + 2 * FF;        // gamma-folded
  float* bcV   = (float*)(wLIN + FF);
  float* uV    = bcV + F;
  float* vV    = uV + F;
  float2* stats = (float2*)(vV + F);             // 16384 float2

  // ---- d_out scratch (compose transients, dead before final GEMM) ----
  unsigned short* DO   = (unsigned short*)d_out;
  unsigned short* wv1T = DO;                     // [F,F]
  unsigned short* wv2T = wv1T + FF;
  unsigned short* tpT  = wv2T + FF;              // [GD,F]
  unsigned short* gpT  = tpT + FG;
  unsigned short* Wc1  = gpT + FG;               // [F,F]
  unsigned short* Wc2  = Wc1 + FF;
  unsigned short* WT1  = Wc2 + FF;               // [F,GD]
  unsigned short* WG2  = WT1 + FG;

  auto conv = [&](const float* src, unsigned short* dst, long n) {
    conv_kernel<<<dim3((unsigned)(n / 8 / 256)), 256, 0, stream>>>(src, dst, (int)n);
  };
  conv(graph, inG, (long)Bm * GD);
  conv(temporal, inT, (long)Bm * GD);
  conv(gp_w, wGP, FG);
  conv(out1_w, wO1b, FF);
  conv(out2_w, wO2b, FF);
  conv(gate_w, wGATE, 2 * FF);
  convs_kernel<<<dim3((unsigned)(FF / 8 / 256)), 256, 0, stream>>>(lin_w, ln_g, wLIN, (int)FF);

  // transposes (fp32 -> bf16^T)
  tconv_kernel<<<dim3(F / 32, F / 32), dim3(32, 8), 0, stream>>>(in1_w + 2 * FF, F, F, wv1T);
  tconv_kernel<<<dim3(F / 32, F / 32), dim3(32, 8), 0, stream>>>(in2_w + 2 * FF, F, F, wv2T);
  tconv_kernel<<<dim3(GD / 32, F / 32), dim3(32, 8), 0, stream>>>(tp_w, F, GD, tpT);
  tconv_kernel<<<dim3(GD / 32, F / 32), dim3(32, 8), 0, stream>>>(gp_w, F, GD, gpT);

  const long NP = 1L << 30;  // pair disabled sentinel
  dim3 blk(512);

  // compose1 (pair): Wc1 = wO1@wv1, Wc2 = wO2@wv2   [2048,2048] K=2048
  gemm8p_kernel<EPI_BIAS, 0><<<dim3(128), blk, 0, stream>>>(
      wO1b, wO1b, F, wv1T, wv1T, F, F, F, F, 8,
      64, wO2b - wO1b, wv2T - wv1T, Wc2 - Wc1,
      nullptr, nullptr, nullptr, nullptr, nullptr, Wc1);
  // compose2 (pair): WT1 = Wc1@tp_w, WG2 = Wc2@gp_w  [2048,1024] K=2048
  gemm8p_kernel<EPI_BIAS, 0><<<dim3(64), blk, 0, stream>>>(
      Wc1, Wc1, F, tpT, tpT, F, F, F, GD, 8,
      32, Wc2 - Wc1, gpT - tpT, WG2 - WT1,
      nullptr, nullptr, nullptr, nullptr, nullptr, WT1);
  // composed bias for cross
  biascomp_kernel<<<dim3(8), dim3(256), 0, stream>>>(
      wO1b, wO2b, Wc1, Wc2, in1_b + 2 * F, in2_b + 2 * F, tp_b, gp_b,
      out1_b, out2_b, bcV);
  // u,v vectors for LN-folded final GEMM
  uv_kernel<<<dim3(8), dim3(256), 0, stream>>>(wLIN, lin_w, ln_b, lin_b, uV, vV);

  // K1: g = graph @ gp_w^T + gp_b          (K=1024) -> S0
  gemm8p_kernel<EPI_BIAS, 1><<<dim3(512), blk, 0, stream>>>(
      inG, inG, GD, wGP, wGP, GD, GD, GD, F, 0, (int)NP, 0, 0, 0,
      gp_b, nullptr, nullptr, nullptr, nullptr, S0);
  // cross = [temporal|graph] @ [WT1;WG2]^T + bcV   (K=2048) -> S1
  gemm8p_kernel<EPI_BIAS, 1><<<dim3(512), blk, 0, stream>>>(
      inT, inG, GD, WT1, WG2, GD, F, GD, F, 0, (int)NP, 0, 0, 0,
      bcV, nullptr, nullptr, nullptr, nullptr, S1);
  // gate+fuse: preLN = gatefuse([g|cross]@gate_w^T + gate_b)  (K=4096) -> PL
  gemm8p_kernel<EPI_GATE, 1><<<dim3(512), blk, 0, stream>>>(
      S0, S1, F, wGATE, wGATE + F, 2 * F, 2 * F, F, F, 0, (int)NP, 0, 0, 0,
      gate_b, nullptr, S0, S1, nullptr, PL);
  // per-row LN stats
  lnstats_kernel<<<dim3(Bm), dim3(256), 0, stream>>>(PL, stats);
  // out = rstd*(preLN @ W'_lin^T) - rstd*mu*u + v   (K=2048, fp32) -> d_out
  gemm8p_kernel<EPI_LNF32, 1><<<dim3(512), blk, 0, stream>>>(
      PL, PL, F, wLIN, wLIN, F, F, F, F, 0, (int)NP, 0, 0, 0,
      uV, vV, nullptr, nullptr, stats, (void*)d_out);
}

// Round 5
// 1030.722 us; speedup vs baseline: 1.1603x; 1.1603x over previous
//
#include <hip/hip_runtime.h>
#include <stdint.h>

typedef __attribute__((ext_vector_type(8))) short short8;
typedef __attribute__((ext_vector_type(4))) float f32x4;

__device__ __forceinline__ unsigned short f2bf(float f) {
  union { float f; uint32_t u; } v; v.f = f;
  uint32_t u = v.u;
  u += 0x7FFF + ((u >> 16) & 1);   // round-to-nearest-even
  return (unsigned short)(u >> 16);
}
__device__ __forceinline__ float bf2f(unsigned short h) {
  union { uint32_t u; float f; } v; v.u = ((uint32_t)h) << 16;
  return v.f;
}

// ---------------- convert fp32 -> bf16 (8 elems/thread) -------------------
__global__ void conv_kernel(const float* __restrict__ in,
                            unsigned short* __restrict__ out, int n) {
  long i = ((long)blockIdx.x * blockDim.x + threadIdx.x) * 8;
  if (i >= n) return;
  float4 a = *(const float4*)(in + i);
  float4 b = *(const float4*)(in + i + 4);
  short8 s;
  s[0] = (short)f2bf(a.x); s[1] = (short)f2bf(a.y);
  s[2] = (short)f2bf(a.z); s[3] = (short)f2bf(a.w);
  s[4] = (short)f2bf(b.x); s[5] = (short)f2bf(b.y);
  s[6] = (short)f2bf(b.z); s[7] = (short)f2bf(b.w);
  *(short8*)(out + i) = s;
}

// concat-convert: src [R][1024] fp32 -> dst[row][colbase + col] bf16, ldo=2048
__global__ void convcat_kernel(const float* __restrict__ in,
                               unsigned short* __restrict__ out,
                               int colbase, int n) {
  long i = ((long)blockIdx.x * blockDim.x + threadIdx.x) * 8;
  if (i >= n) return;
  float4 a = *(const float4*)(in + i);
  float4 b = *(const float4*)(in + i + 4);
  short8 s;
  s[0] = (short)f2bf(a.x); s[1] = (short)f2bf(a.y);
  s[2] = (short)f2bf(a.z); s[3] = (short)f2bf(a.w);
  s[4] = (short)f2bf(b.x); s[5] = (short)f2bf(b.y);
  s[6] = (short)f2bf(b.z); s[7] = (short)f2bf(b.w);
  long row = i >> 10, col = i & 1023;
  *(short8*)(out + row * 2048 + colbase + col) = s;
}

// convert with per-column scale fold: out[i] = bf16(in[i] * scale[i & 2047])
__global__ void convs_kernel(const float* __restrict__ in,
                             const float* __restrict__ scale,
                             unsigned short* __restrict__ out, int n) {
  long i = ((long)blockIdx.x * blockDim.x + threadIdx.x) * 8;
  if (i >= n) return;
  short8 s;
#pragma unroll
  for (int j = 0; j < 8; ++j)
    s[j] = (short)f2bf(in[i + j] * scale[(i + j) & 2047]);
  *(short8*)(out + i) = s;
}

// transpose-convert: out[C][R] = bf16(in[R][C]^T). block (32,8), grid (C/32, R/32)
__global__ void tconv_kernel(const float* __restrict__ in, int R, int C,
                             unsigned short* __restrict__ out) {
  __shared__ float tile[32][33];
  int c0 = blockIdx.x * 32, r0 = blockIdx.y * 32;
  int tx = threadIdx.x, ty = threadIdx.y;
#pragma unroll
  for (int i = 0; i < 32; i += 8)
    tile[ty + i][tx] = in[(long)(r0 + ty + i) * C + c0 + tx];
  __syncthreads();
#pragma unroll
  for (int i = 0; i < 32; i += 8)
    out[(long)(c0 + ty + i) * R + r0 + tx] = f2bf(tile[tx][ty + i]);
}

// ---------------- 256x256 bf16 GEMM, 8-phase, zero-VALU addressing --------
// C = A @ W^T (+ epilogue). BK=64, 8 waves (2M x 4N), interleaved frag map.
// LDS: 2 bufs x (A:2 + B:2 halves) x 16KB = 128KB, chunk-XOR swizzled.
// All ds_read addresses = precomputed base + compile-time immediate.
// Staging = 4 monotone stream pointers (+64 elems per stage event).
// B-fragments register-cached across MQ phase pairs (bqS[2] sets).
enum { EPI_BIAS = 0, EPI_GATE = 2, EPI_LNF32 = 4 };

#define VMW(N) asm volatile("s_waitcnt vmcnt(" #N ")" ::: "memory")
#define SBAR() __builtin_amdgcn_s_barrier()

#define STG(D, OP, HALF, PTR, LD8)                                            \
  { char* lp_ = (char*)smem + ((D)*65536 + (OP)*32768 + (HALF)*16384 + w*2048); \
    __builtin_amdgcn_global_load_lds(                                         \
        (const __attribute__((address_space(1))) void*)(PTR),                 \
        (__attribute__((address_space(3))) void*)lp_, 16, 0, 0);              \
    __builtin_amdgcn_global_load_lds(                                         \
        (const __attribute__((address_space(1))) void*)((PTR) + (LD8)),       \
        (__attribute__((address_space(3))) void*)(lp_ + 1024), 16, 0, 0);     \
    (PTR) += 64; }
#define NOSTG ((void)0)

#define RDA(D, KK) ((KK) ? ((D) ? pA11 : pA01) : ((D) ? pA10 : pA00))
#define RDB(D, KK) ((KK) ? ((D) ? pB11 : pB01) : ((D) ? pB10 : pB00))

template <int EPI, int SWZ>
__global__ __launch_bounds__(512, 2)
void gemm8p_kernel(const unsigned short* __restrict__ A, int lda,
                   const unsigned short* __restrict__ W, int ldw,
                   int K, int ldc, int nmt,
                   int pairBase, long aoff, long woff, long coff,
                   const float* __restrict__ bias,
                   const float* __restrict__ bias2,
                   const unsigned short* __restrict__ Xg,
                   const unsigned short* __restrict__ Xc, int ldx,
                   const float2* __restrict__ stats,
                   void* __restrict__ Cv) {
  __shared__ unsigned short smem[65536];  // 128 KB

  const int tid = threadIdx.x, lane = tid & 63, w = tid >> 6;
  const int wm = w >> 2, wn = w & 3;

  int bid = blockIdx.x;
  if (bid >= pairBase) {
    bid -= pairBase;
    A += aoff; W += woff;
    Cv = (void*)((unsigned short*)Cv + coff);
  }
  int mt, nt;
  if (SWZ) {  // 512 blocks: XCD x owns mt [x*8, x*8+8), sweeps 8 nt
    const int xcd = bid & 7, seq = bid >> 3;
    nt = seq >> 3;
    mt = xcd * 8 + (seq & 7);
  } else {
    mt = bid % nmt;
    nt = bid / nmt;
  }
  const long tileM = (long)mt * 256, tileN = (long)nt * 256;

  // ---- staging stream pointers (monotone, +64 elems per stage event) -----
  const int sRow = w * 16 + (lane >> 3);
  const int sCol = (((lane & 7) ^ ((lane >> 3) & 7)) * 8);
  const unsigned short* pSA0 = A + (tileM + sRow) * (long)lda + sCol;
  const unsigned short* pSA1 = pSA0 + 128 * (long)lda;
  const unsigned short* pSB0 = W + (tileN + sRow) * (long)ldw + sCol;
  const unsigned short* pSB1 = pSB0 + 128 * (long)ldw;
  const long lda8 = 8 * (long)lda, ldw8 = 8 * (long)ldw;

  // ---- LDS read base pointers (per d-buffer x kk), const offsets after ---
  const int fr = lane & 15, kc = lane >> 4, l7 = lane & 7;
  const char* pA00 = (const char*)smem + (wm * 16 + fr) * 128 + ((kc) ^ l7) * 16;
  const char* pA01 = (const char*)smem + (wm * 16 + fr) * 128 + ((4 + kc) ^ l7) * 16;
  const char* pA10 = pA00 + 65536;
  const char* pA11 = pA01 + 65536;
  const char* pB00 = (const char*)smem + 32768 + (wn * 16 + fr) * 128 + ((kc) ^ l7) * 16;
  const char* pB01 = (const char*)smem + 32768 + (wn * 16 + fr) * 128 + ((4 + kc) ^ l7) * 16;
  const char* pB10 = pB00 + 65536;
  const char* pB11 = pB01 + 65536;

  f32x4 acc[8][4] = {};
  short8 aH[4][2];
  short8 bqS[2][2][2];  // [NQ set][ni][kk], all indices compile-time

#define PHASE(D, MQ, NQ, LA, LB, STGX)                                        \
  {                                                                           \
    if (LA) {                                                                 \
      _Pragma("unroll") for (int mi = 0; mi < 4; ++mi) {                      \
        aH[mi][0] = *(const short8*)(RDA(D, 0) + (MQ)*16384 + mi * 4096);     \
        aH[mi][1] = *(const short8*)(RDA(D, 1) + (MQ)*16384 + mi * 4096);     \
      }                                                                       \
    }                                                                         \
    if (LB) {                                                                 \
      _Pragma("unroll") for (int ni = 0; ni < 2; ++ni) {                      \
        bqS[NQ][ni][0] = *(const short8*)(RDB(D, 0) + (NQ)*16384 + ni * 8192);\
        bqS[NQ][ni][1] = *(const short8*)(RDB(D, 1) + (NQ)*16384 + ni * 8192);\
      }                                                                       \
    }                                                                         \
    STGX;                                                                     \
    SBAR();                                                                   \
    __builtin_amdgcn_s_setprio(1);                                            \
    _Pragma("unroll") for (int mi = 0; mi < 4; ++mi)                          \
    _Pragma("unroll") for (int ni = 0; ni < 2; ++ni) {                        \
      acc[(MQ)*4+mi][(NQ)*2+ni] = __builtin_amdgcn_mfma_f32_16x16x32_bf16(    \
          aH[mi][0], bqS[NQ][ni][0], acc[(MQ)*4+mi][(NQ)*2+ni], 0, 0, 0);     \
      acc[(MQ)*4+mi][(NQ)*2+ni] = __builtin_amdgcn_mfma_f32_16x16x32_bf16(    \
          aH[mi][1], bqS[NQ][ni][1], acc[(MQ)*4+mi][(NQ)*2+ni], 0, 0, 0);     \
    }                                                                         \
    __builtin_amdgcn_s_setprio(0);                                            \
  }

  // ---- prologue (identical stage/wait order to proven r3/r4 schedule) ----
  STG(0, 0, 0, pSA0, lda8);  // d0.A0 kt0
  STG(0, 1, 0, pSB0, ldw8);  // d0.B0 kt0
  STG(0, 1, 1, pSB1, ldw8);  // d0.B1 kt0
  STG(0, 0, 1, pSA1, lda8);  // d0.A1 kt0
  STG(1, 0, 0, pSA0, lda8);  // d1.A0 kt1
  STG(1, 1, 0, pSB0, ldw8);  // d1.B0 kt1
  VMW(8);
  SBAR();

  const int NIT = K / 128;  // 2 K-tiles (BK=64) per iteration
  for (int it = 0; it < NIT - 1; ++it) {
    PHASE(0, 0, 0, 1, 1, STG(1, 1, 1, pSB1, ldw8)); VMW(8); SBAR();
    PHASE(0, 0, 1, 0, 1, STG(0, 0, 0, pSA0, lda8)); VMW(8); SBAR();
    PHASE(0, 1, 0, 1, 0, STG(1, 0, 1, pSA1, lda8));         SBAR();
    PHASE(0, 1, 1, 0, 0, STG(0, 1, 0, pSB0, ldw8)); VMW(8); SBAR();
    PHASE(1, 0, 0, 1, 1, STG(0, 1, 1, pSB1, ldw8)); VMW(8); SBAR();
    PHASE(1, 0, 1, 0, 1, STG(0, 0, 1, pSA1, lda8)); VMW(6); SBAR();
    PHASE(1, 1, 0, 1, 0, STG(1, 0, 0, pSA0, lda8));         SBAR();
    PHASE(1, 1, 1, 0, 0, STG(1, 1, 0, pSB0, ldw8)); VMW(8); SBAR();
  }
  {  // peeled drain iteration
    PHASE(0, 0, 0, 1, 1, STG(1, 1, 1, pSB1, ldw8)); VMW(8); SBAR();
    PHASE(0, 0, 1, 0, 1, NOSTG);                    VMW(6); SBAR();
    PHASE(0, 1, 0, 1, 0, STG(1, 0, 1, pSA1, lda8));         SBAR();
    PHASE(0, 1, 1, 0, 0, NOSTG);                    VMW(4); SBAR();
    PHASE(1, 0, 0, 1, 1, NOSTG);                    VMW(2); SBAR();
    PHASE(1, 0, 1, 0, 1, NOSTG);                    VMW(0); SBAR();
    PHASE(1, 1, 0, 1, 0, NOSTG);                            SBAR();
    PHASE(1, 1, 1, 0, 0, NOSTG);
  }
#undef PHASE

  // ---- epilogue: C/D layout col = lane&15, row = (lane>>4)*4 + reg --------
  const int cr = (lane >> 4) * 4;
  const int cc = lane & 15;
#pragma unroll
  for (int m = 0; m < 8; ++m) {
    long rr = tileM + (m >> 2) * 128 + (m & 3) * 32 + wm * 16 + cr;
#pragma unroll
    for (int n = 0; n < 4; ++n) {
      long c = tileN + (n >> 1) * 128 + (n & 1) * 64 + wn * 16 + cc;
      float b1 = bias ? bias[c] : 0.0f;
      float b2 = bias2 ? bias2[c] : 0.0f;
#pragma unroll
      for (int r = 0; r < 4; ++r) {
        long row = rr + r;
        long idx = row * (long)ldc + c;
        float v = acc[m][n][r];
        if constexpr (EPI == EPI_BIAS) {
          ((unsigned short*)Cv)[idx] = f2bf(v + b1 + b2);
        }
        if constexpr (EPI == EPI_GATE) {
          float gt = 1.0f / (1.0f + expf(-(v + b1)));
          long xix = row * (long)ldx + c;
          float gv = bf2f(Xg[xix]);   // g
          float cvv = bf2f(Xc[xix]);  // cross
          ((unsigned short*)Cv)[idx] = f2bf(gt * gv + (1.0f - gt) * cvv + gv);
        }
        if constexpr (EPI == EPI_LNF32) {
          float2 st = stats[row];  // (mu, rstd)
          ((float*)Cv)[idx] = v * st.y - st.y * st.x * b1 + b2;
        }
      }
    }
  }
}

// ---------------- per-row LN stats over 2048 cols -------------------------
__global__ __launch_bounds__(256) void lnstats_kernel(
    const unsigned short* __restrict__ in, float2* __restrict__ stats) {
  const int row = blockIdx.x;
  const int t = threadIdx.x, lane = t & 63, wave = t >> 6;
  short8 v8 = *(const short8*)&in[(long)row * 2048 + t * 8];
  float s = 0.f, s2 = 0.f;
#pragma unroll
  for (int j = 0; j < 8; ++j) {
    float x = bf2f((unsigned short)v8[j]);
    s += x; s2 += x * x;
  }
#pragma unroll
  for (int off = 1; off < 64; off <<= 1) {
    s  += __shfl_xor(s, off);
    s2 += __shfl_xor(s2, off);
  }
  __shared__ float red[8];
  if (lane == 0) { red[wave] = s; red[4 + wave] = s2; }
  __syncthreads();
  if (t == 0) {
    float ts  = red[0] + red[1] + red[2] + red[3];
    float ts2 = red[4] + red[5] + red[6] + red[7];
    float mean = ts * (1.0f / 2048.0f);
    float var  = ts2 * (1.0f / 2048.0f) - mean * mean;
    stats[row] = make_float2(mean, rsqrtf(var + 1e-5f));
  }
}

// bcV[c] = o1b+o2b + wO1b[c]·bv1 + wO2b[c]·bv2 + Wc1[c]·tp_b + Wc2[c]·gp_b
__global__ void biascomp_kernel(const unsigned short* __restrict__ wO1b,
                                const unsigned short* __restrict__ wO2b,
                                const unsigned short* __restrict__ Wc1,
                                const unsigned short* __restrict__ Wc2,
                                const float* __restrict__ bv1,
                                const float* __restrict__ bv2,
                                const float* __restrict__ tpb,
                                const float* __restrict__ gpb,
                                const float* __restrict__ o1b,
                                const float* __restrict__ o2b,
                                float* __restrict__ bcV) {
  int c = blockIdx.x * 256 + threadIdx.x;
  float s = o1b[c] + o2b[c];
  const unsigned short* r1 = wO1b + (long)c * 2048;
  const unsigned short* r2 = wO2b + (long)c * 2048;
  const unsigned short* r3 = Wc1 + (long)c * 2048;
  const unsigned short* r4 = Wc2 + (long)c * 2048;
  for (int k = 0; k < 2048; k += 8) {
    short8 a1 = *(const short8*)(r1 + k);
    short8 a2 = *(const short8*)(r2 + k);
    short8 a3 = *(const short8*)(r3 + k);
    short8 a4 = *(const short8*)(r4 + k);
#pragma unroll
    for (int j = 0; j < 8; ++j)
      s += bf2f((unsigned short)a1[j]) * bv1[k + j]
         + bf2f((unsigned short)a2[j]) * bv2[k + j]
         + bf2f((unsigned short)a3[j]) * tpb[k + j]
         + bf2f((unsigned short)a4[j]) * gpb[k + j];
  }
  bcV[c] = s;
}

// u[n] = rowsum(gamma-folded wLIN);  v[n] = dot(ln_beta, lin_w[n,:]) + lin_b[n]
__global__ void uv_kernel(const unsigned short* __restrict__ wlinp,
                          const float* __restrict__ lin_w,
                          const float* __restrict__ ln_beta,
                          const float* __restrict__ lin_b,
                          float* __restrict__ uV, float* __restrict__ vV) {
  int n = blockIdx.x * 256 + threadIdx.x;
  float u = 0.f, v = 0.f;
  const unsigned short* r1 = wlinp + (long)n * 2048;
  const float* r2 = lin_w + (long)n * 2048;
  for (int k = 0; k < 2048; k += 8) {
    short8 a1 = *(const short8*)(r1 + k);
    float4 f0 = *(const float4*)(r2 + k);
    float4 f1 = *(const float4*)(r2 + k + 4);
    float4 b0 = *(const float4*)(ln_beta + k);
    float4 b1 = *(const float4*)(ln_beta + k + 4);
#pragma unroll
    for (int j = 0; j < 8; ++j) u += bf2f((unsigned short)a1[j]);
    v += b0.x * f0.x + b0.y * f0.y + b0.z * f0.z + b0.w * f0.w
       + b1.x * f1.x + b1.y * f1.y + b1.z * f1.z + b1.w * f1.w;
  }
  uV[n] = u;
  vV[n] = v + lin_b[n];
}

// --------------------------------------------------------------------------
extern "C" void kernel_launch(void* const* d_in, const int* in_sizes, int n_in,
                              void* d_out, int out_size, void* d_ws, size_t ws_size,
                              hipStream_t stream) {
  const float* graph    = (const float*)d_in[0];
  const float* temporal = (const float*)d_in[1];
  const float* gp_w  = (const float*)d_in[2];
  const float* gp_b  = (const float*)d_in[3];
  const float* tp_w  = (const float*)d_in[4];
  const float* tp_b  = (const float*)d_in[5];
  const float* in1_w = (const float*)d_in[6];
  const float* in1_b = (const float*)d_in[7];
  const float* out1_w = (const float*)d_in[8];
  const float* out1_b = (const float*)d_in[9];
  const float* in2_w = (const float*)d_in[10];
  const float* in2_b = (const float*)d_in[11];
  const float* out2_w = (const float*)d_in[12];
  const float* out2_b = (const float*)d_in[13];
  const float* gate_w = (const float*)d_in[14];
  const float* gate_b = (const float*)d_in[15];
  const float* ln_g  = (const float*)d_in[16];
  const float* ln_b  = (const float*)d_in[17];
  const float* lin_w = (const float*)d_in[18];
  const float* lin_b = (const float*)d_in[19];

  const int Bm = 16384, F = 2048, GD = 1024;
  const long BF = (long)Bm * F, FF = (long)F * F, FG = (long)F * GD;

  // ---- ws layout (~210 MB): only what's live during the final GEMM + GX/TG
  unsigned short* GX   = (unsigned short*)d_ws;   // [16384][4096] = [g|cross]
  unsigned short* TG   = GX + (long)Bm * 4096;    // [16384][2048] = [t|g]; later preLN
  unsigned short* PL   = TG;                      // preLN overwrites TG (dead)
  unsigned short* wLIN = TG + BF;                 // gamma-folded lin_w
  float* bcV    = (float*)(wLIN + FF);
  float* uV     = bcV + F;
  float* vV     = uV + F;
  float2* stats = (float2*)(vV + F);              // 16384 float2

  // ---- d_out scratch (88 MB, all dead before final GEMM writes d_out) ----
  unsigned short* DO    = (unsigned short*)d_out;
  unsigned short* wv1T  = DO;           // [2048][2048]
  unsigned short* wv2T  = wv1T + FF;
  unsigned short* tpT   = wv2T + FF;    // [1024][2048]
  unsigned short* gpT   = tpT + FG;
  unsigned short* Wc1   = gpT + FG;     // [2048][2048]
  unsigned short* Wc2   = Wc1 + FF;
  unsigned short* wO1b  = Wc2 + FF;
  unsigned short* wO2b  = wO1b + FF;
  unsigned short* wGATE = wO2b + FF;    // [2048][4096]
  unsigned short* wGP   = wGATE + 2 * FF;  // [2048][1024]
  unsigned short* Wcross = wGP + FG;    // [2048][2048] = [WT1|WG2]

  auto conv = [&](const float* src, unsigned short* dst, long n) {
    conv_kernel<<<dim3((unsigned)(n / 8 / 256)), 256, 0, stream>>>(src, dst, (int)n);
  };
  // inputs -> TG = [temporal | graph]
  convcat_kernel<<<dim3((unsigned)(Bm * GD / 8 / 256)), 256, 0, stream>>>(
      temporal, TG, 0, Bm * GD);
  convcat_kernel<<<dim3((unsigned)(Bm * GD / 8 / 256)), 256, 0, stream>>>(
      graph, TG, GD, Bm * GD);
  conv(gp_w, wGP, FG);
  conv(out1_w, wO1b, FF);
  conv(out2_w, wO2b, FF);
  conv(gate_w, wGATE, 2 * FF);
  convs_kernel<<<dim3((unsigned)(FF / 8 / 256)), 256, 0, stream>>>(lin_w, ln_g, wLIN, (int)FF);
  tconv_kernel<<<dim3(F / 32, F / 32), dim3(32, 8), 0, stream>>>(in1_w + 2 * FF, F, F, wv1T);
  tconv_kernel<<<dim3(F / 32, F / 32), dim3(32, 8), 0, stream>>>(in2_w + 2 * FF, F, F, wv2T);
  tconv_kernel<<<dim3(GD / 32, F / 32), dim3(32, 8), 0, stream>>>(tp_w, F, GD, tpT);
  tconv_kernel<<<dim3(GD / 32, F / 32), dim3(32, 8), 0, stream>>>(gp_w, F, GD, gpT);

  dim3 blk(512);

  // compose1 (pair): Wc1 = wO1@wv1, Wc2 = wO2@wv2   K=2048, N=2048
  gemm8p_kernel<EPI_BIAS, 0><<<dim3(128), blk, 0, stream>>>(
      wO1b, F, wv1T, F, F, F, 8,
      64, wO2b - wO1b, wv2T - wv1T, Wc2 - Wc1,
      nullptr, nullptr, nullptr, nullptr, 0, nullptr, Wc1);
  // compose2 (pair): Wcross = [Wc1@tp_w | Wc2@gp_w]  K=2048, N=1024, coff=1024
  gemm8p_kernel<EPI_BIAS, 0><<<dim3(64), blk, 0, stream>>>(
      Wc1, F, tpT, F, F, F, 8,
      32, Wc2 - Wc1, gpT - tpT, 1024,
      nullptr, nullptr, nullptr, nullptr, 0, nullptr, Wcross);
  biascomp_kernel<<<dim3(8), dim3(256), 0, stream>>>(
      wO1b, wO2b, Wc1, Wc2, in1_b + 2 * F, in2_b + 2 * F, tp_b, gp_b,
      out1_b, out2_b, bcV);
  uv_kernel<<<dim3(8), dim3(256), 0, stream>>>(wLIN, lin_w, ln_b, lin_b, uV, vV);

  // K1: g = graph @ gp_w^T + gp_b   (K=1024) -> GX cols 0..2047 (ldc=4096)
  gemm8p_kernel<EPI_BIAS, 1><<<dim3(512), blk, 0, stream>>>(
      TG + GD, F, wGP, GD, GD, 2 * F, 0, 1 << 30, 0, 0, 0,
      gp_b, nullptr, nullptr, nullptr, 0, nullptr, GX);
  // cross = TG @ Wcross^T + bcV     (K=2048) -> GX cols 2048..4095
  gemm8p_kernel<EPI_BIAS, 1><<<dim3(512), blk, 0, stream>>>(
      TG, F, Wcross, F, F, 2 * F, 0, 1 << 30, 0, 0, 0,
      bcV, nullptr, nullptr, nullptr, 0, nullptr, GX + F);
  // gate+fuse: preLN = gatefuse(GX @ wGATE^T + gate_b)  (K=4096) -> PL (=TG)
  gemm8p_kernel<EPI_GATE, 1><<<dim3(512), blk, 0, stream>>>(
      GX, 2 * F, wGATE, 2 * F, 2 * F, F, 0, 1 << 30, 0, 0, 0,
      gate_b, nullptr, GX, GX + F, 2 * F, nullptr, PL);
  // per-row LN stats
  lnstats_kernel<<<dim3(Bm), dim3(256), 0, stream>>>(PL, stats);
  // out = rstd*(preLN @ wLIN^T) - rstd*mu*u + v   (K=2048, fp32) -> d_out
  gemm8p_kernel<EPI_LNF32, 1><<<dim3(512), blk, 0, stream>>>(
      PL, F, wLIN, F, F, F, 0, 1 << 30, 0, 0, 0,
      uV, vV, nullptr, nullptr, 0, stats, (void*)d_out);
}

// Round 6
// 1012.480 us; speedup vs baseline: 1.1812x; 1.0180x over previous
//
#include <hip/hip_runtime.h>
#include <stdint.h>

typedef __attribute__((ext_vector_type(8))) short short8;
typedef __attribute__((ext_vector_type(4))) float f32x4;

__device__ __forceinline__ unsigned short f2bf(float f) {
  union { float f; uint32_t u; } v; v.f = f;
  uint32_t u = v.u;
  u += 0x7FFF + ((u >> 16) & 1);   // round-to-nearest-even
  return (unsigned short)(u >> 16);
}
__device__ __forceinline__ float bf2f(unsigned short h) {
  union { uint32_t u; float f; } v; v.u = ((uint32_t)h) << 16;
  return v.f;
}

// ---------------- convert fp32 -> bf16 (8 elems/thread) -------------------
__global__ void conv_kernel(const float* __restrict__ in,
                            unsigned short* __restrict__ out, int n) {
  long i = ((long)blockIdx.x * blockDim.x + threadIdx.x) * 8;
  if (i >= n) return;
  float4 a = *(const float4*)(in + i);
  float4 b = *(const float4*)(in + i + 4);
  short8 s;
  s[0] = (short)f2bf(a.x); s[1] = (short)f2bf(a.y);
  s[2] = (short)f2bf(a.z); s[3] = (short)f2bf(a.w);
  s[4] = (short)f2bf(b.x); s[5] = (short)f2bf(b.y);
  s[6] = (short)f2bf(b.z); s[7] = (short)f2bf(b.w);
  *(short8*)(out + i) = s;
}

// concat-convert: src [R][1024] fp32 -> dst[row][colbase + col] bf16, ldo=2048
__global__ void convcat_kernel(const float* __restrict__ in,
                               unsigned short* __restrict__ out,
                               int colbase, int n) {
  long i = ((long)blockIdx.x * blockDim.x + threadIdx.x) * 8;
  if (i >= n) return;
  float4 a = *(const float4*)(in + i);
  float4 b = *(const float4*)(in + i + 4);
  short8 s;
  s[0] = (short)f2bf(a.x); s[1] = (short)f2bf(a.y);
  s[2] = (short)f2bf(a.z); s[3] = (short)f2bf(a.w);
  s[4] = (short)f2bf(b.x); s[5] = (short)f2bf(b.y);
  s[6] = (short)f2bf(b.z); s[7] = (short)f2bf(b.w);
  long row = i >> 10, col = i & 1023;
  *(short8*)(out + row * 2048 + colbase + col) = s;
}

// convert with per-column scale fold: out[i] = bf16(in[i] * scale[i & 2047])
__global__ void convs_kernel(const float* __restrict__ in,
                             const float* __restrict__ scale,
                             unsigned short* __restrict__ out, int n) {
  long i = ((long)blockIdx.x * blockDim.x + threadIdx.x) * 8;
  if (i >= n) return;
  short8 s;
#pragma unroll
  for (int j = 0; j < 8; ++j)
    s[j] = (short)f2bf(in[i + j] * scale[(i + j) & 2047]);
  *(short8*)(out + i) = s;
}

// transpose-convert: out[C][R] = bf16(in[R][C]^T). block (32,8), grid (C/32, R/32)
__global__ void tconv_kernel(const float* __restrict__ in, int R, int C,
                             unsigned short* __restrict__ out) {
  __shared__ float tile[32][33];
  int c0 = blockIdx.x * 32, r0 = blockIdx.y * 32;
  int tx = threadIdx.x, ty = threadIdx.y;
#pragma unroll
  for (int i = 0; i < 32; i += 8)
    tile[ty + i][tx] = in[(long)(r0 + ty + i) * C + c0 + tx];
  __syncthreads();
#pragma unroll
  for (int i = 0; i < 32; i += 8)
    out[(long)(c0 + ty + i) * R + r0 + tx] = f2bf(tile[tx][ty + i]);
}

// ---------------- 256x256 bf16 GEMM, 8-phase, loose counted vmcnt ---------
// C = A @ W^T (+ epilogue). BK=64, 8 waves (2M x 4N), interleaved frag map.
// LDS: 2 bufs x (A:2 + B:2 halves) x 16KB = 128KB, chunk-XOR swizzled.
// Every half restaged the phase AFTER its last read -> 7-phase lead; waits
// VMW(12/10/12/-/12/10/12/-) never stall on HBM. One hw barrier per phase;
// sched_barrier(0) pins {ds+stage | MFMA | boundary} issue order (rule #18).
enum { EPI_BIAS = 0, EPI_GATE = 2, EPI_LNF32 = 4 };

#define VMW(N) asm volatile("s_waitcnt vmcnt(" #N ")" ::: "memory")
#define SBAR() __builtin_amdgcn_s_barrier()
#define SCB() __builtin_amdgcn_sched_barrier(0)

#define STG(D, OP, HALF, PTR, LD8)                                            \
  { char* lp_ = (char*)smem + ((D)*65536 + (OP)*32768 + (HALF)*16384 + w*2048); \
    __builtin_amdgcn_global_load_lds(                                         \
        (const __attribute__((address_space(1))) void*)(PTR),                 \
        (__attribute__((address_space(3))) void*)lp_, 16, 0, 0);              \
    __builtin_amdgcn_global_load_lds(                                         \
        (const __attribute__((address_space(1))) void*)((PTR) + (LD8)),       \
        (__attribute__((address_space(3))) void*)(lp_ + 1024), 16, 0, 0);     \
    (PTR) += 64; }
#define NOSTG ((void)0)

#define RDA(D, KK) ((KK) ? ((D) ? pA11 : pA01) : ((D) ? pA10 : pA00))
#define RDB(D, KK) ((KK) ? ((D) ? pB11 : pB01) : ((D) ? pB10 : pB00))

template <int EPI, int SWZ>
__global__ __launch_bounds__(512, 2)
void gemm8p_kernel(const unsigned short* __restrict__ A, int lda,
                   const unsigned short* __restrict__ W, int ldw,
                   int K, int ldc, int nmt,
                   int pairBase, long aoff, long woff, long coff,
                   const float* __restrict__ bias,
                   const float* __restrict__ bias2,
                   const unsigned short* __restrict__ Xg,
                   const unsigned short* __restrict__ Xc, int ldx,
                   const float2* __restrict__ stats,
                   void* __restrict__ Cv) {
  __shared__ unsigned short smem[65536];  // 128 KB

  const int tid = threadIdx.x, lane = tid & 63, w = tid >> 6;
  const int wm = w >> 2, wn = w & 3;

  int bid = blockIdx.x;
  if (bid >= pairBase) {
    bid -= pairBase;
    A += aoff; W += woff;
    Cv = (void*)((unsigned short*)Cv + coff);
  }
  int mt, nt;
  if (SWZ) {  // 512 blocks: XCD x owns mt [x*8, x*8+8), sweeps 8 nt
    const int xcd = bid & 7, seq = bid >> 3;
    nt = seq >> 3;
    mt = xcd * 8 + (seq & 7);
  } else {
    mt = bid % nmt;
    nt = bid / nmt;
  }
  const long tileM = (long)mt * 256, tileN = (long)nt * 256;

  // ---- staging stream pointers (monotone, +64 elems per stage event) -----
  const int sRow = w * 16 + (lane >> 3);
  const int sCol = (((lane & 7) ^ ((lane >> 3) & 7)) * 8);
  const unsigned short* pSA0 = A + (tileM + sRow) * (long)lda + sCol;
  const unsigned short* pSA1 = pSA0 + 128 * (long)lda;
  const unsigned short* pSB0 = W + (tileN + sRow) * (long)ldw + sCol;
  const unsigned short* pSB1 = pSB0 + 128 * (long)ldw;
  const long lda8 = 8 * (long)lda, ldw8 = 8 * (long)ldw;

  // ---- LDS read base pointers (per d-buffer x kk), const offsets after ---
  const int fr = lane & 15, kc = lane >> 4, l7 = lane & 7;
  const char* pA00 = (const char*)smem + (wm * 16 + fr) * 128 + ((kc) ^ l7) * 16;
  const char* pA01 = (const char*)smem + (wm * 16 + fr) * 128 + ((4 + kc) ^ l7) * 16;
  const char* pA10 = pA00 + 65536;
  const char* pA11 = pA01 + 65536;
  const char* pB00 = (const char*)smem + 32768 + (wn * 16 + fr) * 128 + ((kc) ^ l7) * 16;
  const char* pB01 = (const char*)smem + 32768 + (wn * 16 + fr) * 128 + ((4 + kc) ^ l7) * 16;
  const char* pB10 = pB00 + 65536;
  const char* pB11 = pB01 + 65536;

  f32x4 acc[8][4] = {};
  short8 aH[4][2];
  short8 bqS[2][2][2];  // [NQ set][ni][kk], all indices compile-time

#define PHASE(D, MQ, NQ, LA, LB, STGX)                                        \
  {                                                                           \
    if (LA) {                                                                 \
      _Pragma("unroll") for (int mi = 0; mi < 4; ++mi) {                      \
        aH[mi][0] = *(const short8*)(RDA(D, 0) + (MQ)*16384 + mi * 4096);     \
        aH[mi][1] = *(const short8*)(RDA(D, 1) + (MQ)*16384 + mi * 4096);     \
      }                                                                       \
    }                                                                         \
    if (LB) {                                                                 \
      _Pragma("unroll") for (int ni = 0; ni < 2; ++ni) {                      \
        bqS[NQ][ni][0] = *(const short8*)(RDB(D, 0) + (NQ)*16384 + ni * 8192);\
        bqS[NQ][ni][1] = *(const short8*)(RDB(D, 1) + (NQ)*16384 + ni * 8192);\
      }                                                                       \
    }                                                                         \
    STGX;                                                                     \
    SCB();                                                                    \
    __builtin_amdgcn_s_setprio(1);                                            \
    _Pragma("unroll") for (int mi = 0; mi < 4; ++mi)                          \
    _Pragma("unroll") for (int ni = 0; ni < 2; ++ni) {                        \
      acc[(MQ)*4+mi][(NQ)*2+ni] = __builtin_amdgcn_mfma_f32_16x16x32_bf16(    \
          aH[mi][0], bqS[NQ][ni][0], acc[(MQ)*4+mi][(NQ)*2+ni], 0, 0, 0);     \
      acc[(MQ)*4+mi][(NQ)*2+ni] = __builtin_amdgcn_mfma_f32_16x16x32_bf16(    \
          aH[mi][1], bqS[NQ][ni][1], acc[(MQ)*4+mi][(NQ)*2+ni], 0, 0, 0);     \
    }                                                                         \
    __builtin_amdgcn_s_setprio(0);                                            \
    SCB();                                                                    \
  }

  // ---- prologue: stage both K-tiles fully (16 instrs) --------------------
  STG(0, 0, 0, pSA0, lda8);  // d0.A0 kt0
  STG(0, 1, 0, pSB0, ldw8);  // d0.B0 kt0
  STG(0, 1, 1, pSB1, ldw8);  // d0.B1 kt0
  STG(0, 0, 1, pSA1, lda8);  // d0.A1 kt0
  STG(1, 0, 0, pSA0, lda8);  // d1.A0 kt1
  STG(1, 1, 0, pSB0, ldw8);  // d1.B0 kt1
  STG(1, 1, 1, pSB1, ldw8);  // d1.B1 kt1
  STG(1, 0, 1, pSA1, lda8);  // d1.A1 kt1
  VMW(12);  // d0.A0,B0 arrived
  SBAR();

  const int NIT = K / 128;  // 2 K-tiles (BK=64) per iteration
  for (int it = 0; it < NIT - 1; ++it) {
    // restage each half the phase after its last read; 7-phase lead each
    PHASE(0, 0, 0, 1, 1, NOSTG);                               VMW(10); SBAR();
    PHASE(0, 0, 1, 0, 1, STG(0, 0, 0, pSA0, lda8);
                         STG(0, 1, 0, pSB0, ldw8));            VMW(12); SBAR();
    PHASE(0, 1, 0, 1, 0, STG(0, 1, 1, pSB1, ldw8));                     SBAR();
    PHASE(0, 1, 1, 0, 0, STG(0, 0, 1, pSA1, lda8));            VMW(12); SBAR();
    PHASE(1, 0, 0, 1, 1, NOSTG);                               VMW(10); SBAR();
    PHASE(1, 0, 1, 0, 1, STG(1, 0, 0, pSA0, lda8);
                         STG(1, 1, 0, pSB0, ldw8));            VMW(12); SBAR();
    PHASE(1, 1, 0, 1, 0, STG(1, 1, 1, pSB1, ldw8));                     SBAR();
    PHASE(1, 1, 1, 0, 0, STG(1, 0, 1, pSA1, lda8));            VMW(12); SBAR();
  }
  {  // peeled drain iteration (no stages, monotone drain)
    PHASE(0, 0, 0, 1, 1, NOSTG); VMW(10); SBAR();
    PHASE(0, 0, 1, 0, 1, NOSTG); VMW(8);  SBAR();
    PHASE(0, 1, 0, 1, 0, NOSTG);          SBAR();
    PHASE(0, 1, 1, 0, 0, NOSTG); VMW(4);  SBAR();
    PHASE(1, 0, 0, 1, 1, NOSTG); VMW(2);  SBAR();
    PHASE(1, 0, 1, 0, 1, NOSTG); VMW(0);  SBAR();
    PHASE(1, 1, 0, 1, 0, NOSTG);          SBAR();
    PHASE(1, 1, 1, 0, 0, NOSTG);
  }
#undef PHASE

  // ---- epilogue: C/D layout col = lane&15, row = (lane>>4)*4 + reg --------
  const int cr = (lane >> 4) * 4;
  const int cc = lane & 15;
#pragma unroll
  for (int m = 0; m < 8; ++m) {
    long rr = tileM + (m >> 2) * 128 + (m & 3) * 32 + wm * 16 + cr;
#pragma unroll
    for (int n = 0; n < 4; ++n) {
      long c = tileN + (n >> 1) * 128 + (n & 1) * 64 + wn * 16 + cc;
      float b1 = bias ? bias[c] : 0.0f;
      float b2 = bias2 ? bias2[c] : 0.0f;
#pragma unroll
      for (int r = 0; r < 4; ++r) {
        long row = rr + r;
        long idx = row * (long)ldc + c;
        float v = acc[m][n][r];
        if constexpr (EPI == EPI_BIAS) {
          ((unsigned short*)Cv)[idx] = f2bf(v + b1 + b2);
        }
        if constexpr (EPI == EPI_GATE) {
          float gt = 1.0f / (1.0f + expf(-(v + b1)));
          long xix = row * (long)ldx + c;
          float gv = bf2f(Xg[xix]);   // g
          float cvv = bf2f(Xc[xix]);  // cross
          ((unsigned short*)Cv)[idx] = f2bf(gt * gv + (1.0f - gt) * cvv + gv);
        }
        if constexpr (EPI == EPI_LNF32) {
          float2 st = stats[row];  // (mu, rstd)
          ((float*)Cv)[idx] = v * st.y - st.y * st.x * b1 + b2;
        }
      }
    }
  }
}

// ---------------- per-row LN stats over 2048 cols -------------------------
__global__ __launch_bounds__(256) void lnstats_kernel(
    const unsigned short* __restrict__ in, float2* __restrict__ stats) {
  const int row = blockIdx.x;
  const int t = threadIdx.x, lane = t & 63, wave = t >> 6;
  short8 v8 = *(const short8*)&in[(long)row * 2048 + t * 8];
  float s = 0.f, s2 = 0.f;
#pragma unroll
  for (int j = 0; j < 8; ++j) {
    float x = bf2f((unsigned short)v8[j]);
    s += x; s2 += x * x;
  }
#pragma unroll
  for (int off = 1; off < 64; off <<= 1) {
    s  += __shfl_xor(s, off);
    s2 += __shfl_xor(s2, off);
  }
  __shared__ float red[8];
  if (lane == 0) { red[wave] = s; red[4 + wave] = s2; }
  __syncthreads();
  if (t == 0) {
    float ts  = red[0] + red[1] + red[2] + red[3];
    float ts2 = red[4] + red[5] + red[6] + red[7];
    float mean = ts * (1.0f / 2048.0f);
    float var  = ts2 * (1.0f / 2048.0f) - mean * mean;
    stats[row] = make_float2(mean, rsqrtf(var + 1e-5f));
  }
}

// bcV[c] = o1b+o2b + wO1b[c]·bv1 + wO2b[c]·bv2 + Wc1[c]·tp_b + Wc2[c]·gp_b
__global__ void biascomp_kernel(const unsigned short* __restrict__ wO1b,
                                const unsigned short* __restrict__ wO2b,
                                const unsigned short* __restrict__ Wc1,
                                const unsigned short* __restrict__ Wc2,
                                const float* __restrict__ bv1,
                                const float* __restrict__ bv2,
                                const float* __restrict__ tpb,
                                const float* __restrict__ gpb,
                                const float* __restrict__ o1b,
                                const float* __restrict__ o2b,
                                float* __restrict__ bcV) {
  int c = blockIdx.x * 256 + threadIdx.x;
  float s = o1b[c] + o2b[c];
  const unsigned short* r1 = wO1b + (long)c * 2048;
  const unsigned short* r2 = wO2b + (long)c * 2048;
  const unsigned short* r3 = Wc1 + (long)c * 2048;
  const unsigned short* r4 = Wc2 + (long)c * 2048;
  for (int k = 0; k < 2048; k += 8) {
    short8 a1 = *(const short8*)(r1 + k);
    short8 a2 = *(const short8*)(r2 + k);
    short8 a3 = *(const short8*)(r3 + k);
    short8 a4 = *(const short8*)(r4 + k);
#pragma unroll
    for (int j = 0; j < 8; ++j)
      s += bf2f((unsigned short)a1[j]) * bv1[k + j]
         + bf2f((unsigned short)a2[j]) * bv2[k + j]
         + bf2f((unsigned short)a3[j]) * tpb[k + j]
         + bf2f((unsigned short)a4[j]) * gpb[k + j];
  }
  bcV[c] = s;
}

// u[n] = rowsum(gamma-folded wLIN);  v[n] = dot(ln_beta, lin_w[n,:]) + lin_b[n]
__global__ void uv_kernel(const unsigned short* __restrict__ wlinp,
                          const float* __restrict__ lin_w,
                          const float* __restrict__ ln_beta,
                          const float* __restrict__ lin_b,
                          float* __restrict__ uV, float* __restrict__ vV) {
  int n = blockIdx.x * 256 + threadIdx.x;
  float u = 0.f, v = 0.f;
  const unsigned short* r1 = wlinp + (long)n * 2048;
  const float* r2 = lin_w + (long)n * 2048;
  for (int k = 0; k < 2048; k += 8) {
    short8 a1 = *(const short8*)(r1 + k);
    float4 f0 = *(const float4*)(r2 + k);
    float4 f1 = *(const float4*)(r2 + k + 4);
    float4 b0 = *(const float4*)(ln_beta + k);
    float4 b1 = *(const float4*)(ln_beta + k + 4);
#pragma unroll
    for (int j = 0; j < 8; ++j) u += bf2f((unsigned short)a1[j]);
    v += b0.x * f0.x + b0.y * f0.y + b0.z * f0.z + b0.w * f0.w
       + b1.x * f1.x + b1.y * f1.y + b1.z * f1.z + b1.w * f1.w;
  }
  uV[n] = u;
  vV[n] = v + lin_b[n];
}

// --------------------------------------------------------------------------
extern "C" void kernel_launch(void* const* d_in, const int* in_sizes, int n_in,
                              void* d_out, int out_size, void* d_ws, size_t ws_size,
                              hipStream_t stream) {
  const float* graph    = (const float*)d_in[0];
  const float* temporal = (const float*)d_in[1];
  const float* gp_w  = (const float*)d_in[2];
  const float* gp_b  = (const float*)d_in[3];
  const float* tp_w  = (const float*)d_in[4];
  const float* tp_b  = (const float*)d_in[5];
  const float* in1_w = (const float*)d_in[6];
  const float* in1_b = (const float*)d_in[7];
  const float* out1_w = (const float*)d_in[8];
  const float* out1_b = (const float*)d_in[9];
  const float* in2_w = (const float*)d_in[10];
  const float* in2_b = (const float*)d_in[11];
  const float* out2_w = (const float*)d_in[12];
  const float* out2_b = (const float*)d_in[13];
  const float* gate_w = (const float*)d_in[14];
  const float* gate_b = (const float*)d_in[15];
  const float* ln_g  = (const float*)d_in[16];
  const float* ln_b  = (const float*)d_in[17];
  const float* lin_w = (const float*)d_in[18];
  const float* lin_b = (const float*)d_in[19];

  const int Bm = 16384, F = 2048, GD = 1024;
  const long BF = (long)Bm * F, FF = (long)F * F, FG = (long)F * GD;

  // ---- ws layout (~210 MB): only what's live during the final GEMM + GX/TG
  unsigned short* GX   = (unsigned short*)d_ws;   // [16384][4096] = [g|cross]
  unsigned short* TG   = GX + (long)Bm * 4096;    // [16384][2048] = [t|g]; later preLN
  unsigned short* PL   = TG;                      // preLN overwrites TG (dead)
  unsigned short* wLIN = TG + BF;                 // gamma-folded lin_w
  float* bcV    = (float*)(wLIN + FF);
  float* uV     = bcV + F;
  float* vV     = uV + F;
  float2* stats = (float2*)(vV + F);              // 16384 float2

  // ---- d_out scratch (88 MB, all dead before final GEMM writes d_out) ----
  unsigned short* DO    = (unsigned short*)d_out;
  unsigned short* wv1T  = DO;           // [2048][2048]
  unsigned short* wv2T  = wv1T + FF;
  unsigned short* tpT   = wv2T + FF;    // [1024][2048]
  unsigned short* gpT   = tpT + FG;
  unsigned short* Wc1   = gpT + FG;     // [2048][2048]
  unsigned short* Wc2   = Wc1 + FF;
  unsigned short* wO1b  = Wc2 + FF;
  unsigned short* wO2b  = wO1b + FF;
  unsigned short* wGATE = wO2b + FF;    // [2048][4096]
  unsigned short* wGP   = wGATE + 2 * FF;  // [2048][1024]
  unsigned short* Wcross = wGP + FG;    // [2048][2048] = [WT1|WG2]

  auto conv = [&](const float* src, unsigned short* dst, long n) {
    conv_kernel<<<dim3((unsigned)(n / 8 / 256)), 256, 0, stream>>>(src, dst, (int)n);
  };
  // inputs -> TG = [temporal | graph]
  convcat_kernel<<<dim3((unsigned)(Bm * GD / 8 / 256)), 256, 0, stream>>>(
      temporal, TG, 0, Bm * GD);
  convcat_kernel<<<dim3((unsigned)(Bm * GD / 8 / 256)), 256, 0, stream>>>(
      graph, TG, GD, Bm * GD);
  conv(gp_w, wGP, FG);
  conv(out1_w, wO1b, FF);
  conv(out2_w, wO2b, FF);
  conv(gate_w, wGATE, 2 * FF);
  convs_kernel<<<dim3((unsigned)(FF / 8 / 256)), 256, 0, stream>>>(lin_w, ln_g, wLIN, (int)FF);
  tconv_kernel<<<dim3(F / 32, F / 32), dim3(32, 8), 0, stream>>>(in1_w + 2 * FF, F, F, wv1T);
  tconv_kernel<<<dim3(F / 32, F / 32), dim3(32, 8), 0, stream>>>(in2_w + 2 * FF, F, F, wv2T);
  tconv_kernel<<<dim3(GD / 32, F / 32), dim3(32, 8), 0, stream>>>(tp_w, F, GD, tpT);
  tconv_kernel<<<dim3(GD / 32, F / 32), dim3(32, 8), 0, stream>>>(gp_w, F, GD, gpT);

  dim3 blk(512);

  // compose1 (pair): Wc1 = wO1@wv1, Wc2 = wO2@wv2   K=2048, N=2048
  gemm8p_kernel<EPI_BIAS, 0><<<dim3(128), blk, 0, stream>>>(
      wO1b, F, wv1T, F, F, F, 8,
      64, wO2b - wO1b, wv2T - wv1T, Wc2 - Wc1,
      nullptr, nullptr, nullptr, nullptr, 0, nullptr, Wc1);
  // compose2 (pair): Wcross = [Wc1@tp_w | Wc2@gp_w]  K=2048, N=1024, coff=1024
  gemm8p_kernel<EPI_BIAS, 0><<<dim3(64), blk, 0, stream>>>(
      Wc1, F, tpT, F, F, F, 8,
      32, Wc2 - Wc1, gpT - tpT, 1024,
      nullptr, nullptr, nullptr, nullptr, 0, nullptr, Wcross);
  biascomp_kernel<<<dim3(8), dim3(256), 0, stream>>>(
      wO1b, wO2b, Wc1, Wc2, in1_b + 2 * F, in2_b + 2 * F, tp_b, gp_b,
      out1_b, out2_b, bcV);
  uv_kernel<<<dim3(8), dim3(256), 0, stream>>>(wLIN, lin_w, ln_b, lin_b, uV, vV);

  // K1: g = graph @ gp_w^T + gp_b   (K=1024) -> GX cols 0..2047 (ldc=4096)
  gemm8p_kernel<EPI_BIAS, 1><<<dim3(512), blk, 0, stream>>>(
      TG + GD, F, wGP, GD, GD, 2 * F, 0, 1 << 30, 0, 0, 0,
      gp_b, nullptr, nullptr, nullptr, 0, nullptr, GX);
  // cross = TG @ Wcross^T + bcV     (K=2048) -> GX cols 2048..4095
  gemm8p_kernel<EPI_BIAS, 1><<<dim3(512), blk, 0, stream>>>(
      TG, F, Wcross, F, F, 2 * F, 0, 1 << 30, 0, 0, 0,
      bcV, nullptr, nullptr, nullptr, 0, nullptr, GX + F);
  // gate+fuse: preLN = gatefuse(GX @ wGATE^T + gate_b)  (K=4096) -> PL (=TG)
  gemm8p_kernel<EPI_GATE, 1><<<dim3(512), blk, 0, stream>>>(
      GX, 2 * F, wGATE, 2 * F, 2 * F, F, 0, 1 << 30, 0, 0, 0,
      gate_b, nullptr, GX, GX + F, 2 * F, nullptr, PL);
  // per-row LN stats
  lnstats_kernel<<<dim3(Bm), dim3(256), 0, stream>>>(PL, stats);
  // out = rstd*(preLN @ wLIN^T) - rstd*mu*u + v   (K=2048, fp32) -> d_out
  gemm8p_kernel<EPI_LNF32, 1><<<dim3(512), blk, 0, stream>>>(
      PL, F, wLIN, F, F, F, 0, 1 << 30, 0, 0, 0,
      uV, vV, nullptr, nullptr, 0, stats, (void*)d_out);
}